// Round 3
// baseline (8178.574 us; speedup 1.0000x reference)
//
#include <hip/hip_runtime.h>
#include <hip/hip_bf16.h>

// GraphEncoder: pre-Linear(3->32)+tanh -> GATConv(32->32, skeleton) -> LSTM(768->768, L=256)
// Input/output physically fp32 (proven: bf16 input read -> NaN; bf16 output write -> 0.44 scramble).
//
// d_in: src, W_pre, b_pre, W_gat, att_src, att_dst, b_gat, W_ih, W_hh, b_ih, b_hh
// d_out (fp32): [output 128*256*768][h_n 128*768][c_n 128*768]
//
// ws layout (bytes):
//   0         Xb   bf16 [32768][768]        50331648
//   50331648  WihC bf16 [3072][768]          4718592
//   55050240  WhhC bf16 [3072][768]          4718592
//   59768832  cs   fp32 [128][768]            393216
//   60162048  h0   bf16 [128][768]            196608
//   60358656  h1   bf16 [128][768]            196608
//   60555264  smallC fp32 [8192]               32768
//   60588032  flag int32

#define NB 128
#define LSEQ 256
#define LH 768
#define BGR 32768

typedef __attribute__((ext_vector_type(8))) short short8;
typedef __attribute__((ext_vector_type(4))) float floatx4;

__device__ __forceinline__ float load_in(const void* p, long i, int bf) {
    return bf ? __bfloat162float(((const __hip_bfloat16*)p)[i])
              : ((const float*)p)[i];
}

// ---------------- Sniff input dtype (safety net; expect fp32 -> flag 0) ----------------
__global__ void sniff_kernel(const unsigned int* __restrict__ w, int* __restrict__ flag) {
    int cnt = 0;
    for (int i = threadIdx.x; i < 256; i += 64) {
        unsigned int lo = (w[i] & 0xFFFFu) << 16;
        float v = __uint_as_float(lo);
        float a = fabsf(v);
        if (a > 9.5e-7f && a < 8.0f) cnt++;
    }
    #pragma unroll
    for (int k = 32; k >= 1; k >>= 1) cnt += __shfl_xor(cnt, k);
    if (threadIdx.x == 0) *flag = (cnt >= 128) ? 1 : 0;
}

// ---------------- Canonicalize weights ----------------
// smallC float layout: W_pre@0(96) b_pre@96(32) W_gat@128(1024) att_src@1152(32)
//                      att_dst@1184(32) b_gat@1216(32) b_ih@1248(3072) b_hh@4320(3072)
__global__ __launch_bounds__(256) void convert_kernel(
    const void* W_pre, const void* b_pre, const void* W_gat,
    const void* att_src, const void* att_dst, const void* b_gat,
    const void* W_ih, const void* W_hh, const void* b_ih, const void* b_hh,
    const int* __restrict__ flagp,
    __hip_bfloat16* __restrict__ WihC, __hip_bfloat16* __restrict__ WhhC,
    float* __restrict__ smallC)
{
    long i = (long)blockIdx.x * 256 + threadIdx.x;
    const int bf = *flagp;
    if (i < 2359296) { WihC[i] = __float2bfloat16(load_in(W_ih, i, bf)); return; }
    i -= 2359296;
    if (i < 2359296) { WhhC[i] = __float2bfloat16(load_in(W_hh, i, bf)); return; }
    i -= 2359296;
    if (i < 96)   { smallC[0 + i]    = load_in(W_pre, i, bf);   return; }  i -= 96;
    if (i < 32)   { smallC[96 + i]   = load_in(b_pre, i, bf);   return; }  i -= 32;
    if (i < 1024) { smallC[128 + i]  = load_in(W_gat, i, bf);   return; }  i -= 1024;
    if (i < 32)   { smallC[1152 + i] = load_in(att_src, i, bf); return; }  i -= 32;
    if (i < 32)   { smallC[1184 + i] = load_in(att_dst, i, bf); return; }  i -= 32;
    if (i < 32)   { smallC[1216 + i] = load_in(b_gat, i, bf);   return; }  i -= 32;
    if (i < 3072) { smallC[1248 + i] = load_in(b_ih, i, bf);    return; }  i -= 3072;
    if (i < 3072) { smallC[4320 + i] = load_in(b_hh, i, bf);    return; }
}

// ---------------- Kernel A: pre + GAT -> Xb (bf16) ----------------
__global__ __launch_bounds__(256) void gat_pre_kernel(
    const void* __restrict__ src,            // [32768][72]
    const float* __restrict__ smallC,
    const int* __restrict__ flagp,
    __hip_bfloat16* __restrict__ Xb)         // [32768][768]
{
    __shared__ float wpre[96];
    __shared__ float bpre[32];
    __shared__ float wgat[1024];
    __shared__ float asrc[32];
    __shared__ float adst[32];
    __shared__ float bgat[32];
    __shared__ float xl[8][72];
    __shared__ float hl[8][24][32];
    __shared__ float xpl[8][24][32];
    __shared__ float asl[8][24];
    __shared__ float adl[8][24];

    const int tid = threadIdx.x;
    const int bf = *flagp;
    for (int i = tid; i < 96; i += 256)   wpre[i] = smallC[i];
    for (int i = tid; i < 1024; i += 256) wgat[i] = smallC[128 + i];
    if (tid < 32) {
        bpre[tid] = smallC[96 + tid];
        asrc[tid] = smallC[1152 + tid];
        adst[tid] = smallC[1184 + tid];
        bgat[tid] = smallC[1216 + tid];
    }

    const int g = tid >> 5;
    const int k = tid & 31;
    const long gb = (long)blockIdx.x * 8 + g;   // graph id = n*256 + t

    for (int i = k; i < 72; i += 32)
        xl[g][i] = load_in(src, gb * 72 + i, bf);
    __syncthreads();

    #pragma unroll
    for (int j = 0; j < 24; ++j) {
        float v = xl[g][j*3+0] * wpre[0*32+k]
                + xl[g][j*3+1] * wpre[1*32+k]
                + xl[g][j*3+2] * wpre[2*32+k] + bpre[k];
        hl[g][j][k] = tanhf(v);
    }
    __syncthreads();

    #pragma unroll
    for (int j = 0; j < 24; ++j) {
        float v = 0.f;
        #pragma unroll
        for (int m = 0; m < 32; ++m) v += hl[g][j][m] * wgat[m*32 + k];
        xpl[g][j][k] = v;
    }
    __syncthreads();

    if (k < 24) {
        float vs = 0.f, vd = 0.f;
        #pragma unroll
        for (int m = 0; m < 32; ++m) {
            float x = xpl[g][k][m];
            vs += x * asrc[m];
            vd += x * adst[m];
        }
        asl[g][k] = vs;
        adl[g][k] = vd;
    }
    __syncthreads();

    const int par[24] = {-1,0,0,0,1,2,3,4,5,6,7,8,9,9,9,12,13,14,16,17,18,19,20,21};
    #pragma unroll
    for (int j = 0; j < 24; ++j) {
        int p = par[j];
        float o;
        if (p < 0) {
            o = xpl[g][j][k] + bgat[k];
        } else {
            float es = adl[g][j] + asl[g][j];
            float ep = adl[g][j] + asl[g][p];
            es = es > 0.f ? es : 0.2f * es;
            ep = ep > 0.f ? ep : 0.2f * ep;
            float mx = fmaxf(es, ep);
            float wse = expf(es - mx), wpe = expf(ep - mx);
            float inv = 1.f / (wse + wpe);
            o = (wse * xpl[g][j][k] + wpe * xpl[g][p][k]) * inv + bgat[k];
        }
        Xb[gb * 768 + j * 32 + k] = __float2bfloat16(o);
    }
}

// ---------------- Kernel C: one LSTM step ----------------
// 96 WGs x 256 threads; WG b owns hidden units [8b,8b+8), all 4 gates (32 gate cols).
// gates[128x32] via mfma 16x16x32 bf16. Ping-pong h: read hr=h[t&1], write hw=h[(t+1)&1].
__global__ __launch_bounds__(256) void lstm_step_kernel(
    const __hip_bfloat16* __restrict__ Xb,    // [32768][768]
    const __hip_bfloat16* __restrict__ Wih,   // [3072][768]
    const __hip_bfloat16* __restrict__ Whh,   // [3072][768]
    const float* __restrict__ smallC,
    float* __restrict__ cst,                  // [128][768] fp32
    const __hip_bfloat16* __restrict__ hr,
    __hip_bfloat16* __restrict__ hw,
    float* __restrict__ out,                  // fp32 [128][256][768]
    int t)
{
    __shared__ float gl[128 * 33];

    const int tid = threadIdx.x;
    const int w = tid >> 6;
    const int L = tid & 63;
    const int rh = w >> 1;
    const int ct = w & 1;
    const int q = L >> 4;
    const int col16 = L & 15;
    const int c_local = 16 * ct + col16;
    const int gate = c_local >> 3;
    const int uu = c_local & 7;
    const int u = 8 * blockIdx.x + uu;
    const int wrow = 768 * gate + u;

    const short8* bp_i = (const short8*)(Wih + (long)wrow * 768 + q * 8);
    const short8* bp_h = (const short8*)(Whh + (long)wrow * 768 + q * 8);

    const short8* ap_x[4];
    const short8* ap_h[4];
    #pragma unroll
    for (int rt = 0; rt < 4; ++rt) {
        int m = 64 * rh + 16 * rt + col16;
        ap_x[rt] = (const short8*)(Xb + ((long)m * LSEQ + t) * 768 + q * 8);
        ap_h[rt] = (const short8*)(hr + (long)m * 768 + q * 8);
    }

    floatx4 acc[4] = {};

    for (int kk = 0; kk < 768; kk += 32) {
        short8 bv = bp_i[kk >> 3];
        #pragma unroll
        for (int rt = 0; rt < 4; ++rt) {
            short8 av = ap_x[rt][kk >> 3];
            acc[rt] = __builtin_amdgcn_mfma_f32_16x16x32_bf16(av, bv, acc[rt], 0, 0, 0);
        }
    }
    for (int kk = 0; kk < 768; kk += 32) {
        short8 bv = bp_h[kk >> 3];
        #pragma unroll
        for (int rt = 0; rt < 4; ++rt) {
            short8 av = ap_h[rt][kk >> 3];
            acc[rt] = __builtin_amdgcn_mfma_f32_16x16x32_bf16(av, bv, acc[rt], 0, 0, 0);
        }
    }

    float bias = smallC[1248 + wrow] + smallC[4320 + wrow];
    #pragma unroll
    for (int rt = 0; rt < 4; ++rt) {
        #pragma unroll
        for (int r = 0; r < 4; ++r) {
            int m = 64 * rh + 16 * rt + q * 4 + r;   // C/D: col=lane&15, row=quad*4+reg
            gl[m * 33 + c_local] = acc[rt][r] + bias;
        }
    }
    __syncthreads();

    for (int item = tid; item < 1024; item += 256) {
        int m = item >> 3;
        int u2l = item & 7;
        float ig = gl[m * 33 + 0  + u2l];
        float fg = gl[m * 33 + 8  + u2l];
        float gg = gl[m * 33 + 16 + u2l];
        float og = gl[m * 33 + 24 + u2l];
        int u2 = 8 * blockIdx.x + u2l;
        int ci = m * 768 + u2;
        float co = cst[ci];
        float si = 1.f / (1.f + expf(-ig));
        float sf = 1.f / (1.f + expf(-fg));
        float so = 1.f / (1.f + expf(-og));
        float cn = sf * co + si * tanhf(gg);
        float h = so * tanhf(cn);
        cst[ci] = cn;
        hw[ci] = __float2bfloat16(h);
        out[((long)m * LSEQ + t) * 768 + u2] = h;   // fp32 output
    }
}

// ---------------- finalize h_n / c_n (fp32) ----------------
__global__ __launch_bounds__(256) void finalize_kernel(
    const __hip_bfloat16* __restrict__ hfin,
    const float* __restrict__ cst,
    float* __restrict__ out)
{
    int i = blockIdx.x * 256 + threadIdx.x;
    const long base = (long)NB * LSEQ * LH;
    out[base + i] = __bfloat162float(hfin[i]);
    out[base + NB * LH + i] = cst[i];
}

extern "C" void kernel_launch(void* const* d_in, const int* in_sizes, int n_in,
                              void* d_out, int out_size, void* d_ws, size_t ws_size,
                              hipStream_t stream) {
    const void* src     = d_in[0];
    const void* W_pre   = d_in[1];
    const void* b_pre   = d_in[2];
    const void* W_gat   = d_in[3];
    const void* att_src = d_in[4];
    const void* att_dst = d_in[5];
    const void* b_gat   = d_in[6];
    const void* W_ih    = d_in[7];
    const void* W_hh    = d_in[8];
    const void* b_ih    = d_in[9];
    const void* b_hh    = d_in[10];

    float* out = (float*)d_out;
    char* ws = (char*)d_ws;

    __hip_bfloat16* Xb     = (__hip_bfloat16*)(ws);
    __hip_bfloat16* WihC   = (__hip_bfloat16*)(ws + 50331648);
    __hip_bfloat16* WhhC   = (__hip_bfloat16*)(ws + 55050240);
    float*          cs     = (float*)         (ws + 59768832);
    __hip_bfloat16* h0     = (__hip_bfloat16*)(ws + 60162048);
    __hip_bfloat16* h1     = (__hip_bfloat16*)(ws + 60358656);
    float*          smallC = (float*)         (ws + 60555264);
    int*            flagp  = (int*)           (ws + 60588032);

    hipMemsetAsync(cs, 0, NB * LH * sizeof(float), stream);
    hipMemsetAsync(h0, 0, NB * LH * sizeof(__hip_bfloat16), stream);

    sniff_kernel<<<1, 64, 0, stream>>>((const unsigned int*)src, flagp);

    const long conv_total = 2359296L * 2 + 7392;
    convert_kernel<<<(int)((conv_total + 255) / 256), 256, 0, stream>>>(
        W_pre, b_pre, W_gat, att_src, att_dst, b_gat,
        W_ih, W_hh, b_ih, b_hh, flagp, WihC, WhhC, smallC);

    gat_pre_kernel<<<BGR / 8, 256, 0, stream>>>(src, smallC, flagp, Xb);

    __hip_bfloat16* hp[2] = {h0, h1};
    for (int t = 0; t < LSEQ; ++t) {
        lstm_step_kernel<<<96, 256, 0, stream>>>(Xb, WihC, WhhC, smallC,
                                                 cs, hp[t & 1], hp[(t + 1) & 1],
                                                 out, t);
    }

    finalize_kernel<<<NB * LH / 256, 256, 0, stream>>>(h0, cs, out);
}